// Round 1
// baseline (607.519 us; speedup 1.0000x reference)
//
#include <hip/hip_runtime.h>
#include <math.h>

#define DIM     2048
#define NEXP    64
#define CAP     128
#define NTOK    8192
#define NTILE   256            // 256 tiles of 32 tokens
#define KC      256            // K-chunk staged in LDS
#define NCH     (DIM/KC)       // 8 chunks
#define XWSTR   260            // row stride for xs/ws tiles (KC+4)
#define PSTR    68             // row stride for partial/logit tiles
#define RF      67108864       // floats per output region (S*E*C)
#define RF4     16777216       // RF/4 (f4 units)
#define FBLK    2048           // fill blocks
#define FCH     16384          // f4 per fill block (256 KB)

typedef float vfloat4 __attribute__((ext_vector_type(4)));

// ---- 1. gate GEMM + softmax/argmax/rank (R9 structure, fill REMOVED) ----
// Without the NT stores, the per-chunk vmcnt(0) barrier only drains the
// 12 staging loads (latency ~1 us/chunk) instead of a 256 KB store batch.
__global__ __launch_bounds__(512, 2) void gate(
    const float* __restrict__ x, const float* __restrict__ wg,
    int* __restrict__ expert_idx, float* __restrict__ gate_top,
    int* __restrict__ rank,
    float* __restrict__ me_partial, int* __restrict__ counts)
{
    __shared__ __align__(16) float smem[(32 + NEXP) * XWSTR]; // 99,840 B
    __shared__ float me_w[8 * NEXP];
    __shared__ int   cnt_w[8 * NEXP];
    __shared__ int   exp_s[32];

    float* xs = smem;                 // [32][XWSTR]
    float* ws = smem + 32 * XWSTR;    // [64][XWSTR]

    const int tid  = threadIdx.x;
    const int gb   = blockIdx.x;
    const int tok0 = gb * 32;
    const int sl   = tid >> 5;        // k-slice 0..15
    const int i    = tid & 31;
    const int tg   = i & 3;           // token group
    const int eg   = i >> 2;          // expert group 0..7
    const int kb   = sl * 16;         // slice's kk base within chunk

    float acc[8][8] = {};

    for (int ch = 0; ch < NCH; ++ch) {
        const int k0 = ch * KC;
        #pragma unroll
        for (int q = 0; q < 4; ++q) {
            int id = tid + (q << 9);
            int r = id >> 6, c = id & 63;
            float4 v = *(const float4*)(x + (size_t)(tok0 + r) * DIM + k0 + 4 * c);
            *(float4*)(&xs[r * XWSTR + 4 * c]) = v;
        }
        #pragma unroll
        for (int q = 0; q < 8; ++q) {
            int id = tid + (q << 9);
            int r = id >> 6, c = id & 63;
            float4 v = *(const float4*)(wg + (size_t)r * DIM + k0 + 4 * c);
            *(float4*)(&ws[r * XWSTR + 4 * c]) = v;
        }
        __syncthreads();

        #pragma unroll
        for (int q2 = 0; q2 < 4; ++q2) {
            const int kk = kb + 4 * q2;
            float4 xt[8], we[8];
            #pragma unroll
            for (int j = 0; j < 8; ++j)
                xt[j] = *(const float4*)(&xs[(tg + 4 * j) * XWSTR + kk]);
            #pragma unroll
            for (int m = 0; m < 8; ++m)
                we[m] = *(const float4*)(&ws[(eg + 8 * m) * XWSTR + kk]);
            #pragma unroll
            for (int j = 0; j < 8; ++j)
                #pragma unroll
                for (int m = 0; m < 8; ++m) {
                    acc[j][m] = fmaf(xt[j].x, we[m].x, acc[j][m]);
                    acc[j][m] = fmaf(xt[j].y, we[m].y, acc[j][m]);
                    acc[j][m] = fmaf(xt[j].z, we[m].z, acc[j][m]);
                    acc[j][m] = fmaf(xt[j].w, we[m].w, acc[j][m]);
                }
        }
        __syncthreads();
    }

    // ---- reduce 16 k-slices through LDS ----
    float* part = smem;                 // [8][32][PSTR]
    float* lgt  = smem + 8 * 32 * PSTR; // [32][PSTR]
    if (sl >= 8) {
        #pragma unroll
        for (int j = 0; j < 8; ++j)
            #pragma unroll
            for (int m = 0; m < 8; ++m)
                part[((sl - 8) * 32 + tg + 4 * j) * PSTR + eg + 8 * m] = acc[j][m];
    }
    __syncthreads();
    if (sl < 8) {
        #pragma unroll
        for (int j = 0; j < 8; ++j)
            #pragma unroll
            for (int m = 0; m < 8; ++m) {
                int idx = (sl * 32 + tg + 4 * j) * PSTR + eg + 8 * m;
                part[idx] += acc[j][m];
            }
    }
    __syncthreads();

    {
        int t  = tid >> 4;
        int e0 = (tid & 15) << 2;
        float4 a = {0, 0, 0, 0};
        #pragma unroll
        for (int s2 = 0; s2 < 8; ++s2) {
            float4 p = *(const float4*)(&part[(s2 * 32 + t) * PSTR + e0]);
            a.x += p.x; a.y += p.y; a.z += p.z; a.w += p.w;
        }
        *(float4*)(&lgt[t * PSTR + e0]) = a;
    }
    __syncthreads();

    // ---- softmax + argmax: 8 waves x 4 rows, lane = expert ----
    const int lane = tid & 63;
    const int wv   = tid >> 6;
    float me_acc  = 0.0f;
    int   cnt_acc = 0;
    #pragma unroll
    for (int r4 = 0; r4 < 4; ++r4) {
        int row = wv * 4 + r4;
        float v = lgt[row * PSTR + lane];
        float m = v; int mi = lane;
        #pragma unroll
        for (int off = 32; off > 0; off >>= 1) {
            float om  = __shfl_xor(m, off);
            int   omi = __shfl_xor(mi, off);
            if (om > m || (om == m && omi < mi)) { m = om; mi = omi; }
        }
        float ex = __expf(v - m);
        float sm = ex;
        #pragma unroll
        for (int off = 32; off > 0; off >>= 1) sm += __shfl_xor(sm, off);
        me_acc += ex / sm;
        if (lane == mi) {
            expert_idx[tok0 + row] = mi;
            gate_top[tok0 + row]   = 1.0f / sm;
            exp_s[row] = mi;
            ++cnt_acc;
        }
    }
    me_w[wv * NEXP + lane]  = me_acc;
    cnt_w[wv * NEXP + lane] = cnt_acc;
    __syncthreads();

    if (tid < 32) {   // within-tile rank (token order)
        int e = exp_s[tid];
        int rk = 0;
        for (int u = 0; u < tid; ++u) rk += (exp_s[u] == e) ? 1 : 0;
        rank[tok0 + tid] = rk;
    }
    if (tid < NEXP) {
        float ms = 0.f; int cs = 0;
        #pragma unroll
        for (int w = 0; w < 8; ++w) { ms += me_w[w * NEXP + tid]; cs += cnt_w[w * NEXP + tid]; }
        me_partial[gb * NEXP + tid] = ms;
        counts[gb * NEXP + tid]     = cs;
    }
}

// ---- 2. prefix + l_aux + COMPACT per-token target position ----
// Replaces 16K scattered single-CU line-miss stores with a coalesced 32 KB
// pos_g[] write; the scattered traffic moves to fill_patch's 2048 blocks.
__global__ __launch_bounds__(1024) void prefix_pos(
    const float* __restrict__ me_partial, const int* __restrict__ counts,
    const int* __restrict__ expert_idx, const int* __restrict__ rank,
    int* __restrict__ pos_g, float* __restrict__ laux)
{
    __shared__ int   bo_l[NTILE * NEXP];   // 64 KB exclusive offsets
    __shared__ int   cnt_l[16 * NEXP];
    __shared__ float me_l[16 * NEXP];
    __shared__ int   cnt_tot[NEXP];
    __shared__ float me_tot[NEXP];

    const int tid = threadIdx.x;
    const int e   = tid & 63;
    const int g   = tid >> 6;          // 0..15

    int cs = 0; float ms = 0.f;
    #pragma unroll
    for (int i = 0; i < 16; ++i) {
        int t = g * 16 + i;
        cs += counts[t * NEXP + e];
        ms += me_partial[t * NEXP + e];
    }
    cnt_l[g * NEXP + e] = cs;
    me_l[g * NEXP + e]  = ms;
    __syncthreads();

    if (g == 0) {
        int run = 0; float mt = 0.f;
        #pragma unroll
        for (int i = 0; i < 16; ++i) {
            int c = cnt_l[i * NEXP + e];
            cnt_l[i * NEXP + e] = run;
            run += c;
            mt  += me_l[i * NEXP + e];
        }
        cnt_tot[e] = run;
        me_tot[e]  = mt;
    }
    __syncthreads();

    int run = cnt_l[g * NEXP + e];
    #pragma unroll
    for (int i = 0; i < 16; ++i) {
        int t = g * 16 + i;
        bo_l[t * NEXP + e] = run;
        run += counts[t * NEXP + e];
    }
    __syncthreads();

    if (tid < NEXP) {
        float v = (me_tot[e] / (float)NTOK) * ((float)cnt_tot[e] / (float)NTOK);
        #pragma unroll
        for (int off = 32; off > 0; off >>= 1) v += __shfl_xor(v, off);
        if (e == 0) laux[0] = v * (float)NEXP;   // mean(me*ce)*E*E == sum*E
    }

    #pragma unroll
    for (int ii = 0; ii < 8; ++ii) {
        int s  = tid + (ii << 10);
        int ex = expert_idx[s];
        int loc = bo_l[(s >> 5) * NEXP + ex] + rank[s];
        // final float index in out[], or -1 if dropped (fits int: max 67108864)
        pos_g[s] = (loc < CAP) ? (1 + s * (NEXP * CAP) + ex * CAP + loc) : -1;
    }
}

// ---- 3. zero-fill at full write BW + in-range patch ----
// fillBufferAligned-shaped: 32 back-to-back NT f4 stores per thread, no
// waits inside the loop (no LDS -> 4 blocks/CU resident, drains overlap).
// After one barrier (vmcnt(0) drain of this block's stores), <=18 threads
// patch the candidate tokens whose nonzero lands in this block's f4 range.
// Ranges partition [0, 2*RF/4) exactly (+1 f4 slot on the last block for
// the out[2*RF] corner), so each patch is written by exactly one block.
__global__ __launch_bounds__(512) void fill_patch(
    const int* __restrict__ pos_g, const float* __restrict__ gate_top,
    const float* __restrict__ laux, float* __restrict__ out)
{
    const int tid = threadIdx.x;
    const int b   = blockIdx.x;
    vfloat4* o4 = reinterpret_cast<vfloat4*>(out);
    const vfloat4 z4 = {0.f, 0.f, 0.f, 0.f};

    const size_t base = (size_t)b * FCH + tid;
    #pragma unroll
    for (int k = 0; k < 32; ++k)
        __builtin_nontemporal_store(z4, &o4[base + (size_t)(k << 9)]);
    if (b == FBLK - 1 && tid == 511)
        out[134217728ull] = 0.0f;      // the one float past the f4 span (2*RF)
    __syncthreads();                   // drains this block's fill stores

    // Candidate tokens: block b covers f4 [b*FCH, b*FCH+FCH). A combine row
    // s spans f4 [2048s, 2048(s+1)] (the +1-float skew), so combine
    // candidates are s in {8b-1 .. 8b+7}; dispatch rows sit +RF4 f4 higher,
    // so dispatch candidates are s in {8(b-1024)-1 .. 8(b-1024)+7}.
    if (tid < 18) {
        const int isD = tid >= 9;
        const int r   = tid - 9 * isD;          // 0..8
        const int sb  = isD ? (b - 1024) : b;
        const int s   = 8 * sb - 1 + r;
        if (s >= 0 && s < NTOK) {
            const int p = pos_g[s];
            if (p >= 0) {
                const int gi = p + (isD ? RF : 0);   // max 134217728, fits int
                const int F  = gi >> 2;
                const int lo = b * FCH;
                const int hi = lo + FCH + ((b == FBLK - 1) ? 1 : 0);
                if (F >= lo && F < hi)
                    out[(size_t)gi] = isD ? 1.0f : gate_top[s];
            }
        }
    }
    if (b == 0 && tid == 18) out[0] = laux[0];   // l_aux (after fill of f4 0)
}

extern "C" void kernel_launch(void* const* d_in, const int* in_sizes, int n_in,
                              void* d_out, int out_size, void* d_ws, size_t ws_size,
                              hipStream_t stream)
{
    const float* x  = (const float*)d_in[0];
    const float* wg = (const float*)d_in[1];
    float* out = (float*)d_out;

    char* ws = (char*)d_ws;
    int*   expert_idx = (int*)  (ws);             // 32 KB
    float* gate_top   = (float*)(ws + 32768);     // 32 KB
    int*   rank       = (int*)  (ws + 65536);     // 32 KB
    float* me_partial = (float*)(ws + 98304);     // 64 KB
    int*   counts     = (int*)  (ws + 163840);    // 64 KB
    int*   pos_g      = (int*)  (ws + 229376);    // 32 KB
    float* laux       = (float*)(ws + 262144);    // 4 B   (total 256 KB + 4)

    gate<<<NTILE, 512, 0, stream>>>(x, wg, expert_idx, gate_top, rank,
                                    me_partial, counts);
    prefix_pos<<<1, 1024, 0, stream>>>(me_partial, counts, expert_idx, rank,
                                       pos_g, laux);
    fill_patch<<<FBLK, 512, 0, stream>>>(pos_g, gate_top, laux, out);
}